// Round 12
// baseline (88.426 us; speedup 1.0000x reference)
//
#include <hip/hip_runtime.h>

typedef __attribute__((ext_vector_type(8))) short bf16x8;
typedef __attribute__((ext_vector_type(4))) float f32x4;

constexpr int N_PTS = 16384;
constexpr int KN = 16;    // neighbors
constexpr int P  = 15;    // kernel points
constexpr int CI = 64;
constexpr int CO = 128;
constexpr int QB = 32;    // query points per block
constexpr int KTOT   = P * CI;     // 960
constexpr int KSTEPS = KTOT / 32;  // 30
constexpr int APITCH = KTOT + 8;   // 968 shorts/row
constexpr int PF = 4;              // phase-C B-prefetch depth
constexpr size_t FB_OFF = 262144;  // feats_bf16 [M][CI] ws offset (2 MB)

static __device__ __forceinline__ unsigned short f2bf(float f) {
    unsigned u = __float_as_uint(f);
    u = (u + 0x7fffu + ((u >> 16) & 1u)) >> 16;  // RNE
    return (unsigned short)u;
}
#define BFLO(u) __uint_as_float((unsigned)(u) << 16)
#define BFHI(u) __uint_as_float((unsigned)(u) & 0xFFFF0000u)

// ---- Prep: W -> bf16 fragments WB[kstep][ntile][lane][8]; feats -> bf16 ----
__global__ __launch_bounds__(256) void prep(const float* __restrict__ W,
                                            const float* __restrict__ feats,
                                            unsigned short* __restrict__ WB,
                                            unsigned short* __restrict__ featsB) {
    const int t = blockIdx.x * 256 + threadIdx.x;   // 128 blocks

    {   // feats: 262144 float4 chunks (4 MB), coalesced
        const float4* src = (const float4*)feats;
        #pragma unroll
        for (int i = 0; i < 8; ++i) {
            const int e = i * 32768 + t;
            const float4 v = src[e];
            uint2 o;
            o.x = f2bf(v.x) | ((unsigned)f2bf(v.y) << 16);
            o.y = f2bf(v.z) | ((unsigned)f2bf(v.w) << 16);
            *(uint2*)&featsB[(size_t)e * 4] = o;
        }
    }
    if (t < 15360) {   // WB fragments
        const int l  = t & 63;
        const int kb = (t >> 9) * 32 + ((l >> 4) * 8);
        const int o  = ((t >> 6) & 7) * 16 + (l & 15);
        unsigned short v[8];
        #pragma unroll
        for (int j = 0; j < 8; ++j) v[j] = f2bf(W[(size_t)(kb + j) * CO + o]);
        uint4 q;
        q.x = v[0] | ((unsigned)v[1] << 16);
        q.y = v[2] | ((unsigned)v[3] << 16);
        q.z = v[4] | ((unsigned)v[5] << 16);
        q.w = v[6] | ((unsigned)v[7] << 16);
        *(uint4*)&WB[(size_t)t * 8] = q;
    }
}

__global__ __launch_bounds__(512, 4) void kpconv_main(
    const float* __restrict__ query,    // [N][3]
    const float* __restrict__ support,  // [M][3]
    const int*   __restrict__ nidx,     // [N][KN]
    const unsigned short* __restrict__ featsB,  // bf16 [M][CI]
    const unsigned short* __restrict__ WB,
    const float* __restrict__ kp,       // [P][3]
    float* __restrict__ out)            // [N][CO]
{
    __shared__ float sKp[P][3];
    __shared__ unsigned short sIdxS[QB][KN];                      // 1 KB
    __shared__ __align__(16) unsigned short sInflB[QB][KN][16];   // 16 KB
    __shared__ __align__(16) unsigned short sAgg[QB][APITCH];     // 60.5 KB

    const int t  = threadIdx.x;
    const int n0 = blockIdx.x * QB;
    const int w  = t >> 6, l = t & 63;
    const int pt = t >> 4, x = t & 15;
    const int n  = n0 + pt;
    const int c  = 4 * x;

    // ---- A-1: read own neighbor idx; issue geometry loads early ----
    const int myIdx = nidx[n * KN + x];
    sIdxS[pt][x] = (unsigned short)myIdx;
    const float sx = support[myIdx * 3 + 0];
    const float sy = support[myIdx * 3 + 1];
    const float sz = support[myIdx * 3 + 2];
    const float qx = query[n * 3 + 0];
    const float qy = query[n * 3 + 1];
    const float qz = query[n * 3 + 2];
    if (t < P * 3) ((float*)sKp)[t] = kp[t];
    __syncthreads();

    // ---- A-2: issue first-half feats-row prefetch (k = 0..7), independent ----
    const uint4 iv0 = *(const uint4*)&sIdxS[pt][0];   // k0..7 packed ushorts
    const uint4 iv1 = *(const uint4*)&sIdxS[pt][8];   // k8..15
    #define ROWLD(word, hi) \
        (*(const uint2*)&featsB[(size_t)((hi) ? ((word) >> 16) : ((word) & 0xFFFFu)) * CI + c])
    const uint2 f0 = ROWLD(iv0.x, 0);
    const uint2 f1 = ROWLD(iv0.x, 1);
    const uint2 f2 = ROWLD(iv0.y, 0);
    const uint2 f3 = ROWLD(iv0.y, 1);
    const uint2 f4 = ROWLD(iv0.z, 0);
    const uint2 f5 = ROWLD(iv0.z, 1);
    const uint2 f6 = ROWLD(iv0.w, 0);
    const uint2 f7 = ROWLD(iv0.w, 1);

    // ---- A-3: geometry (hides prefetch latency); write infl bf16 ----
    {
        const float rx = sx - qx, ry = sy - qy, rz = sz - qz;
        unsigned short h[16];
        #pragma unroll
        for (int p = 0; p < P; ++p) {
            const float dx = rx - sKp[p][0];
            const float dy = ry - sKp[p][1];
            const float dz = rz - sKp[p][2];
            h[p] = f2bf(fmaxf(1.0f - sqrtf(dx*dx + dy*dy + dz*dz), 0.0f));
        }
        h[15] = 0;
        uint4 u0, u1;
        u0.x = h[0] | ((unsigned)h[1] << 16);   u0.y = h[2] | ((unsigned)h[3] << 16);
        u0.z = h[4] | ((unsigned)h[5] << 16);   u0.w = h[6] | ((unsigned)h[7] << 16);
        u1.x = h[8] | ((unsigned)h[9] << 16);   u1.y = h[10] | ((unsigned)h[11] << 16);
        u1.z = h[12] | ((unsigned)h[13] << 16); u1.w = h[14];
        *(uint4*)&sInflB[pt][x][0] = u0;
        *(uint4*)&sInflB[pt][x][8] = u1;
    }
    __syncthreads();

    // ---- Phase B: issue second-half prefetch, then unrolled dense FMA ----
    {
        const uint2 f8  = ROWLD(iv1.x, 0);
        const uint2 f9  = ROWLD(iv1.x, 1);
        const uint2 f10 = ROWLD(iv1.y, 0);
        const uint2 f11 = ROWLD(iv1.y, 1);
        const uint2 f12 = ROWLD(iv1.z, 0);
        const uint2 f13 = ROWLD(iv1.z, 1);
        const uint2 f14 = ROWLD(iv1.w, 0);
        const uint2 f15 = ROWLD(iv1.w, 1);

        f32x4 A0={0,0,0,0},A1={0,0,0,0},A2={0,0,0,0},A3={0,0,0,0},A4={0,0,0,0};
        f32x4 A5={0,0,0,0},A6={0,0,0,0},A7={0,0,0,0},A8={0,0,0,0},A9={0,0,0,0};
        f32x4 A10={0,0,0,0},A11={0,0,0,0},A12={0,0,0,0},A13={0,0,0,0},A14={0,0,0,0};

        #define FMA_K(FR, K)                                                    \
            do {                                                                \
                const uint4 u0 = *(const uint4*)&sInflB[pt][K][0];              \
                const uint4 u1 = *(const uint4*)&sInflB[pt][K][8];              \
                const f32x4 fv = { BFLO(FR.x), BFHI(FR.x),                      \
                                   BFLO(FR.y), BFHI(FR.y) };                    \
                A0  += BFLO(u0.x) * fv;  A1  += BFHI(u0.x) * fv;                \
                A2  += BFLO(u0.y) * fv;  A3  += BFHI(u0.y) * fv;                \
                A4  += BFLO(u0.z) * fv;  A5  += BFHI(u0.z) * fv;                \
                A6  += BFLO(u0.w) * fv;  A7  += BFHI(u0.w) * fv;                \
                A8  += BFLO(u1.x) * fv;  A9  += BFHI(u1.x) * fv;                \
                A10 += BFLO(u1.y) * fv;  A11 += BFHI(u1.y) * fv;                \
                A12 += BFLO(u1.z) * fv;  A13 += BFHI(u1.z) * fv;                \
                A14 += BFLO(u1.w) * fv;                                         \
            } while (0)
        FMA_K(f0, 0);   FMA_K(f1, 1);   FMA_K(f2, 2);   FMA_K(f3, 3);
        FMA_K(f4, 4);   FMA_K(f5, 5);   FMA_K(f6, 6);   FMA_K(f7, 7);
        FMA_K(f8, 8);   FMA_K(f9, 9);   FMA_K(f10, 10); FMA_K(f11, 11);
        FMA_K(f12, 12); FMA_K(f13, 13); FMA_K(f14, 14); FMA_K(f15, 15);
        #undef FMA_K
        #undef ROWLD

        #define STORE_P(p, Ap)                                                  \
            do {                                                                \
                uint2 wv;                                                       \
                wv.x = f2bf(Ap.x) | ((unsigned)f2bf(Ap.y) << 16);               \
                wv.y = f2bf(Ap.z) | ((unsigned)f2bf(Ap.w) << 16);               \
                *(uint2*)&sAgg[pt][(p) * CI + c] = wv;                          \
            } while (0)
        STORE_P(0, A0);  STORE_P(1, A1);  STORE_P(2, A2);  STORE_P(3, A3);
        STORE_P(4, A4);  STORE_P(5, A5);  STORE_P(6, A6);  STORE_P(7, A7);
        STORE_P(8, A8);  STORE_P(9, A9);  STORE_P(10, A10); STORE_P(11, A11);
        STORE_P(12, A12); STORE_P(13, A13); STORE_P(14, A14);
        #undef STORE_P
    }
    __syncthreads();

    // ---- Phase C: wave w -> ntile w, rows 0..31; PF=4 B-prefetch ----
    {
        f32x4 c0 = {0.f, 0.f, 0.f, 0.f};
        f32x4 c1 = {0.f, 0.f, 0.f, 0.f};
        const int kq = (l >> 4) * 8;
        const unsigned short* a0 = &sAgg[l & 15][kq];
        const unsigned short* a1 = &sAgg[16 + (l & 15)][kq];
        const unsigned short* wb = &WB[(size_t)(w * 64 + l) * 8];
        bf16x8 pb[PF];
        #pragma unroll
        for (int s = 0; s < PF; ++s) pb[s] = *(const bf16x8*)&wb[(size_t)s * 4096];
        #pragma unroll
        for (int s = 0; s < KSTEPS; ++s) {
            const bf16x8 av0 = *(const bf16x8*)&a0[s * 32];
            const bf16x8 av1 = *(const bf16x8*)&a1[s * 32];
            const bf16x8 bv = pb[s & (PF - 1)];
            c0 = __builtin_amdgcn_mfma_f32_16x16x32_bf16(av0, bv, c0, 0, 0, 0);
            c1 = __builtin_amdgcn_mfma_f32_16x16x32_bf16(av1, bv, c1, 0, 0, 0);
            if (s + PF < KSTEPS) pb[s & (PF - 1)] = *(const bf16x8*)&wb[(size_t)(s + PF) * 4096];
        }
        const int o0 = w * 16 + (l & 15);
        const int r0 = n0 + (l >> 4) * 4;
        #pragma unroll
        for (int r = 0; r < 4; ++r) {
            out[(size_t)(r0 + r) * CO + o0]      = c0[r];
            out[(size_t)(r0 + 16 + r) * CO + o0] = c1[r];
        }
    }
}

extern "C" void kernel_launch(void* const* d_in, const int* in_sizes, int n_in,
                              void* d_out, int out_size, void* d_ws, size_t ws_size,
                              hipStream_t stream) {
    const float* query   = (const float*)d_in[0];
    const float* support = (const float*)d_in[1];
    const int*   nidx    = (const int*)d_in[2];
    const float* feats   = (const float*)d_in[3];
    const float* W       = (const float*)d_in[4];
    const float* kp      = (const float*)d_in[5];
    float* out = (float*)d_out;
    unsigned short* WB     = (unsigned short*)d_ws;
    unsigned short* featsB = (unsigned short*)((char*)d_ws + FB_OFF);

    hipLaunchKernelGGL(prep, dim3(128), dim3(256), 0, stream, W, feats, WB, featsB);
    hipLaunchKernelGGL(kpconv_main, dim3(N_PTS / QB), dim3(512), 0, stream,
                       query, support, nidx, featsB, WB, kp, out);
}

// Round 13
// 87.909 us; speedup vs baseline: 1.0059x; 1.0059x over previous
//
#include <hip/hip_runtime.h>

typedef __attribute__((ext_vector_type(8))) short bf16x8;
typedef __attribute__((ext_vector_type(4))) float f32x4;

constexpr int N_PTS = 16384;
constexpr int KN = 16;    // neighbors
constexpr int P  = 15;    // kernel points
constexpr int CI = 64;
constexpr int CO = 128;
constexpr int QB = 32;    // query points per block
constexpr int KTOT   = P * CI;     // 960
constexpr int KSTEPS = KTOT / 32;  // 30
constexpr int APITCH = KTOT + 8;   // 968 shorts/row
constexpr int PF = 4;              // B-prefetch depth
constexpr size_t TOUCH_OFF = 262144;  // touch-sink ws offset (512 KB)

static __device__ __forceinline__ unsigned short f2bf(float f) {
    unsigned u = __float_as_uint(f);
    u = (u + 0x7fffu + ((u >> 16) & 1u)) >> 16;  // RNE
    return (unsigned short)u;
}
#define BFLO(u) __uint_as_float((unsigned)(u) << 16)
#define BFHI(u) __uint_as_float((unsigned)(u) & 0xFFFF0000u)

// ---- Prep: WB fragment conversion + warm-everything streaming touch ----
// Touch set (16B chunks): nidx 65536 | query 12288 | support 12288 | feats 262144
__global__ __launch_bounds__(256) void prep(const float* __restrict__ W,
                                            const float* __restrict__ feats,
                                            const int*   __restrict__ nidx,
                                            const float* __restrict__ query,
                                            const float* __restrict__ support,
                                            unsigned short* __restrict__ WB,
                                            unsigned* __restrict__ touchOut) {
    const int t = blockIdx.x * 256 + threadIdx.x;   // 512 blocks -> 131072 threads

    // (a) streaming touch, coalesced, XOR-kept-live
    unsigned acc = 0;
    #pragma unroll
    for (int j = 0; j < 3; ++j) {
        const int c = j * 131072 + t;
        if (c < 352256) {
            const uint4* p;
            if (c < 65536)       p = (const uint4*)nidx    + c;
            else if (c < 77824)  p = (const uint4*)query   + (c - 65536);
            else if (c < 90112)  p = (const uint4*)support + (c - 77824);
            else                 p = (const uint4*)feats   + (c - 90112);
            const uint4 v = *p;
            acc ^= v.x ^ v.y ^ v.z ^ v.w;
        }
    }
    touchOut[t] = acc;

    // (b) WB fragments [kstep][ntile][lane][8] (reads all of W)
    if (t < 15360) {
        const int l  = t & 63;
        const int kb = (t >> 9) * 32 + ((l >> 4) * 8);
        const int o  = ((t >> 6) & 7) * 16 + (l & 15);
        unsigned short v[8];
        #pragma unroll
        for (int j = 0; j < 8; ++j) v[j] = f2bf(W[(size_t)(kb + j) * CO + o]);
        uint4 q;
        q.x = v[0] | ((unsigned)v[1] << 16);
        q.y = v[2] | ((unsigned)v[3] << 16);
        q.z = v[4] | ((unsigned)v[5] << 16);
        q.w = v[6] | ((unsigned)v[7] << 16);
        *(uint4*)&WB[(size_t)t * 8] = q;
    }
}

// ---- Main: byte-identical to R9 (best measured: 86.2) ----
__global__ __launch_bounds__(512, 4) void kpconv_main(
    const float* __restrict__ query,    // [N][3]
    const float* __restrict__ support,  // [M][3]
    const int*   __restrict__ nidx,     // [N][KN]
    const float* __restrict__ feats,    // [M][CI]
    const unsigned short* __restrict__ WB,
    const float* __restrict__ kp,       // [P][3]
    float* __restrict__ out)            // [N][CO]
{
    __shared__ float sKp[P][3];
    __shared__ unsigned short sIdxS[QB][KN];
    __shared__ int sCnt[QB];
    __shared__ unsigned char sKlist[QB][KN];
    __shared__ __align__(16) unsigned short sInflB[QB][KN][16];   // 16 KB
    __shared__ __align__(16) unsigned short sAgg[QB][APITCH];     // 60.5 KB

    const int t  = threadIdx.x;
    const int n0 = blockIdx.x * QB;
    const int w  = t >> 6, l = t & 63;

    if (t < P * 3) ((float*)sKp)[t] = kp[t];
    if (t < QB) sCnt[t] = 0;
    __syncthreads();

    // ---- Phase A: thread (pt = t>>4, k = t&15); compact active k's ----
    {
        const int pt = t >> 4, k = t & 15;
        const int n = n0 + pt;
        const int idx = nidx[n * KN + k];
        sIdxS[pt][k] = (unsigned short)idx;
        const float rx = support[idx * 3 + 0] - query[n * 3 + 0];
        const float ry = support[idx * 3 + 1] - query[n * 3 + 1];
        const float rz = support[idx * 3 + 2] - query[n * 3 + 2];
        unsigned short h[16];
        float mx = 0.0f;
        #pragma unroll
        for (int p = 0; p < P; ++p) {
            const float dx = rx - sKp[p][0];
            const float dy = ry - sKp[p][1];
            const float dz = rz - sKp[p][2];
            const float infl = fmaxf(1.0f - sqrtf(dx*dx + dy*dy + dz*dz), 0.0f);
            mx = fmaxf(mx, infl);
            h[p] = f2bf(infl);
        }
        h[15] = 0;
        uint4 u0, u1;
        u0.x = h[0] | ((unsigned)h[1] << 16);   u0.y = h[2] | ((unsigned)h[3] << 16);
        u0.z = h[4] | ((unsigned)h[5] << 16);   u0.w = h[6] | ((unsigned)h[7] << 16);
        u1.x = h[8] | ((unsigned)h[9] << 16);   u1.y = h[10] | ((unsigned)h[11] << 16);
        u1.z = h[12] | ((unsigned)h[13] << 16); u1.w = h[14];
        *(uint4*)&sInflB[pt][k][0] = u0;
        *(uint4*)&sInflB[pt][k][8] = u1;
        if (mx > 0.0f) {
            const int slot = atomicAdd(&sCnt[pt], 1);
            sKlist[pt][slot] = (unsigned char)k;
        }
    }
    __syncthreads();

    // ---- Phase B: thread (pt = t>>4, c = (t&15)*4); only active k ----
    {
        const int pt = t >> 4;
        const int c  = (t & 15) * 4;
        const int nk = sCnt[pt];
        f32x4 A0={0,0,0,0},A1={0,0,0,0},A2={0,0,0,0},A3={0,0,0,0},A4={0,0,0,0};
        f32x4 A5={0,0,0,0},A6={0,0,0,0},A7={0,0,0,0},A8={0,0,0,0},A9={0,0,0,0};
        f32x4 A10={0,0,0,0},A11={0,0,0,0},A12={0,0,0,0},A13={0,0,0,0},A14={0,0,0,0};
        for (int i = 0; i < nk; ++i) {
            const int k   = sKlist[pt][i];
            const int idx = sIdxS[pt][k];
            const f32x4 fv = *(const f32x4*)&feats[(size_t)idx * CI + c];
            const uint4 u0 = *(const uint4*)&sInflB[pt][k][0];
            const uint4 u1 = *(const uint4*)&sInflB[pt][k][8];
            A0  += BFLO(u0.x) * fv;  A1  += BFHI(u0.x) * fv;
            A2  += BFLO(u0.y) * fv;  A3  += BFHI(u0.y) * fv;
            A4  += BFLO(u0.z) * fv;  A5  += BFHI(u0.z) * fv;
            A6  += BFLO(u0.w) * fv;  A7  += BFHI(u0.w) * fv;
            A8  += BFLO(u1.x) * fv;  A9  += BFHI(u1.x) * fv;
            A10 += BFLO(u1.y) * fv;  A11 += BFHI(u1.y) * fv;
            A12 += BFLO(u1.z) * fv;  A13 += BFHI(u1.z) * fv;
            A14 += BFLO(u1.w) * fv;
        }
        #define STORE_P(p, Ap)                                                  \
            do {                                                                \
                uint2 wv;                                                       \
                wv.x = f2bf(Ap.x) | ((unsigned)f2bf(Ap.y) << 16);               \
                wv.y = f2bf(Ap.z) | ((unsigned)f2bf(Ap.w) << 16);               \
                *(uint2*)&sAgg[pt][(p) * CI + c] = wv;                          \
            } while (0)
        STORE_P(0, A0);  STORE_P(1, A1);  STORE_P(2, A2);  STORE_P(3, A3);
        STORE_P(4, A4);  STORE_P(5, A5);  STORE_P(6, A6);  STORE_P(7, A7);
        STORE_P(8, A8);  STORE_P(9, A9);  STORE_P(10, A10); STORE_P(11, A11);
        STORE_P(12, A12); STORE_P(13, A13); STORE_P(14, A14);
        #undef STORE_P
    }
    __syncthreads();

    // ---- Phase C: wave w -> ntile w, rows 0..31; PF=4 B-prefetch ----
    {
        f32x4 c0 = {0.f, 0.f, 0.f, 0.f};
        f32x4 c1 = {0.f, 0.f, 0.f, 0.f};
        const int kq = (l >> 4) * 8;
        const unsigned short* a0 = &sAgg[l & 15][kq];
        const unsigned short* a1 = &sAgg[16 + (l & 15)][kq];
        const unsigned short* wb = &WB[(size_t)(w * 64 + l) * 8];
        bf16x8 pb[PF];
        #pragma unroll
        for (int s = 0; s < PF; ++s) pb[s] = *(const bf16x8*)&wb[(size_t)s * 4096];
        #pragma unroll
        for (int s = 0; s < KSTEPS; ++s) {
            const bf16x8 av0 = *(const bf16x8*)&a0[s * 32];
            const bf16x8 av1 = *(const bf16x8*)&a1[s * 32];
            const bf16x8 bv = pb[s & (PF - 1)];
            c0 = __builtin_amdgcn_mfma_f32_16x16x32_bf16(av0, bv, c0, 0, 0, 0);
            c1 = __builtin_amdgcn_mfma_f32_16x16x32_bf16(av1, bv, c1, 0, 0, 0);
            if (s + PF < KSTEPS) pb[s & (PF - 1)] = *(const bf16x8*)&wb[(size_t)(s + PF) * 4096];
        }
        const int o0 = w * 16 + (l & 15);
        const int r0 = n0 + (l >> 4) * 4;
        #pragma unroll
        for (int r = 0; r < 4; ++r) {
            out[(size_t)(r0 + r) * CO + o0]      = c0[r];
            out[(size_t)(r0 + 16 + r) * CO + o0] = c1[r];
        }
    }
}

extern "C" void kernel_launch(void* const* d_in, const int* in_sizes, int n_in,
                              void* d_out, int out_size, void* d_ws, size_t ws_size,
                              hipStream_t stream) {
    const float* query   = (const float*)d_in[0];
    const float* support = (const float*)d_in[1];
    const int*   nidx    = (const int*)d_in[2];
    const float* feats   = (const float*)d_in[3];
    const float* W       = (const float*)d_in[4];
    const float* kp      = (const float*)d_in[5];
    float* out = (float*)d_out;
    unsigned short* WB = (unsigned short*)d_ws;                       // 245760 B
    unsigned* touchOut = (unsigned*)((char*)d_ws + TOUCH_OFF);        // 512 KB

    hipLaunchKernelGGL(prep, dim3(512), dim3(256), 0, stream,
                       W, feats, nidx, query, support, WB, touchOut);
    hipLaunchKernelGGL(kpconv_main, dim3(N_PTS / QB), dim3(512), 0, stream,
                       query, support, nidx, feats, WB, kp, out);
}